// Round 18
// baseline (167.481 us; speedup 1.0000x reference)
//
#include <hip/hip_runtime.h>
#include <math.h>

typedef _Float16 f16x8 __attribute__((ext_vector_type(8)));
typedef float f32x4 __attribute__((ext_vector_type(4)));
typedef unsigned int u32;
typedef unsigned long long u64;

#define NBATCH 32
#define CIN    64
#define COUT   192
#define HWD    56
#define KR     4
#define NKQ    14

#define WS_W_OFF  1024

#define SBAR()  do { __builtin_amdgcn_s_barrier(); asm volatile("" ::: "memory"); } while(0)
#define WAITL() asm volatile("s_waitcnt lgkmcnt(0)" ::: "memory")

struct KArgs {
    float bt[49];
    float einit[7];
};

// AT transposed: ATT[v][u] = AT[u][v]
__device__ const float ATT[7][5] = {
    {1,0,0,0,0},{1,1,1,1,1},{1,-1,1,-1,1},{1,2,4,8,16},{1,-2,4,-8,16},{1,3,9,27,81},{0,0,0,0,1}};

// ---------------- Host: Householder QR lstsq for BT (f64) + range flag ----------------
static void host_compute_bt(KArgs* ka, bool* dual) {
    const double ATd[5][7] = {
        {1,1,1,1,1,1,0},{0,1,-1,2,-2,3,0},{0,1,1,4,4,9,0},{0,1,-1,8,-8,27,0},{0,1,1,16,16,81,1}};
    const double pts[6] = {0.0,1.0,-1.0,2.0,-2.0,3.0};
    double G[7][3];
    for (int i=0;i<6;i++){ G[i][0]=1.0; G[i][1]=pts[i]; G[i][2]=pts[i]*pts[i]; }
    G[6][0]=0.0; G[6][1]=0.0; G[6][2]=1.0;
    double M[15][7], T[15][7];
    for (int p=0;p<3;p++)
        for (int u=0;u<5;u++)
            for (int v=0;v<7;v++)
                M[5*p+u][v] = ATd[u][v]*G[v][p];
    for (int i=0;i<15;i++) for (int j=0;j<7;j++) T[i][j]=0.0;
    for (int p=0;p<3;p++) for (int kk=0;kk<5;kk++) T[5*p+kk][kk+p]=1.0;
    for (int j=0;j<7;j++){
        double sig=0.0; for (int i=j;i<15;i++) sig += M[i][j]*M[i][j];
        double nrm = sqrt(sig);
        double ajj = M[j][j];
        double alpha = (ajj > 0.0) ? -nrm : nrm;
        double v[15];
        v[j] = ajj - alpha;
        for (int i=j+1;i<15;i++) v[i] = M[i][j];
        double vtv = sig - 2.0*alpha*ajj + alpha*alpha;
        if (vtv > 1e-300) {
            double tau = 2.0/vtv;
            for (int c=j;c<7;c++){
                double s=0.0; for (int i=j;i<15;i++) s += v[i]*M[i][c];
                s *= tau;
                for (int i=j;i<15;i++) M[i][c] -= s*v[i];
            }
            for (int c=0;c<7;c++){
                double s=0.0; for (int i=j;i<15;i++) s += v[i]*T[i][c];
                s *= tau;
                for (int i=j;i<15;i++) T[i][c] -= s*v[i];
            }
        }
        M[j][j] = alpha;
        for (int i=j+1;i<15;i++) M[i][j]=0.0;
    }
    double btd[49];
    for (int c=0;c<7;c++){
        double xs[7];
        for (int i=6;i>=0;i--){
            double s = T[i][c];
            for (int k2=i+1;k2<7;k2++) s -= M[i][k2]*xs[k2];
            xs[i] = s / M[i][i];
        }
        for (int i=0;i<7;i++) btd[i*7+c] = xs[i];
    }
    for (int i=0;i<49;i++) ka->bt[i] = (float)btd[i];
    double mb = 0.0;
    for (int v=0;v<7;v++){
        double rs = 0.0;
        for (int c=0;c<7;c++) rs += fabs(btd[v*7+c]);
        if (rs > mb) mb = rs;
    }
    *dual = (mb * 128.0 > 8192.0);
    for (int v=0;v<7;v++){
        float s = ka->bt[v*7+0];
        for (int w=1;w<7;w++) s = s + ka->bt[v*7+w];
        ka->einit[v] = -128.f * s;
    }
}

// ---------------- Kernel: weight transform -> per-(step,ng12) 1KB frag layout ----------------
__global__ void wt16_kernel(const float* __restrict__ w, _Float16* __restrict__ W3) {
    int idx = blockIdx.x*256 + threadIdx.x;     // chunk id, < 7*6*12*64 = 32256
    if (idx >= 32256) return;
    const int lane = idx & 63;
    int t = idx >> 6;
    const int ng = t % 12; t /= 12;
    const int step = t % 6; t /= 6;
    const int v = t;
    const int l15 = lane & 15, g = lane >> 4;
    const int rr = step >> 1, ch = step & 1;
    const int o = ng*16 + l15;
    const float Gf[7][3] = {{1,0,0},{1,1,1},{1,-1,1},{1,2,4},{1,-2,4},{1,3,9},{0,0,1}};
    const float g0 = Gf[v][0], g1 = Gf[v][1], g2 = Gf[v][2];
    f16x8 outv;
    #pragma unroll
    for (int e = 0; e < 8; ++e) {
        const int c = ch*32 + g*8 + e;
        const float* wp = w + (((size_t)o*CIN + c)*3 + rr)*3;
        float val = wp[0]*g0 + wp[1]*g1 + wp[2]*g2;
        val = rintf(val);
        val = fminf(fmaxf(val, -32768.f), 32767.f);
        outv[e] = (_Float16)val;
    }
    *(f16x8*)(W3 + (size_t)idx*8) = outv;
}

// ---------------- Main kernel: 2-plane ping-pong, phase-slipped S||G, 4 waves/SIMD ----------------

#define BLOAD(S, sl) do { \
    br[sl] = *(const f16x8*)(W + (size_t)((S)*12 + ng)*512 + lane*8); \
} while (0)

#define E_BUILD(vv, PH, PL) do { \
    const float b0 = ka.bt[(vv)*7+0], b1 = ka.bt[(vv)*7+1], b2 = ka.bt[(vv)*7+2]; \
    const float b3 = ka.bt[(vv)*7+3], b4 = ka.bt[(vv)*7+4], b5 = ka.bt[(vv)*7+5]; \
    const float b6 = ka.bt[(vv)*7+6]; \
    const float einit = ka.einit[(vv)]; \
    _Pragma("unroll") \
    for (int krow = 0; krow < 6; ++krow) { \
        const u32 Aw = xwL[krow], Bw = xwH[krow]; \
        float e = einit; \
        e = fmaf(b0, (float)(Aw & 255u),         e); \
        e = fmaf(b1, (float)((Aw >> 8) & 255u),  e); \
        e = fmaf(b2, (float)((Aw >> 16) & 255u), e); \
        e = fmaf(b3, (float)(Aw >> 24),          e); \
        e = fmaf(b4, (float)(Bw & 255u),         e); \
        e = fmaf(b5, (float)((Bw >> 8) & 255u),  e); \
        e = fmaf(b6, (float)((Bw >> 16) & 255u), e); \
        e = rintf(e); \
        e = fminf(fmaxf(e, -32768.f), 32767.f); \
        const int row = krow*12 + t_e; \
        const int sb = row*128 + ((((cc >> 3) ^ (row & 7)) << 4) | ((cc & 7) << 1)); \
        if (DUAL) { \
            float ehs = rintf(e * (1.f/2048.f)) * 2048.f; \
            *(_Float16*)(lds + (PH) + sb) = (_Float16)ehs; \
            *(_Float16*)(lds + (PL) + sb) = (_Float16)(e - ehs); \
        } else { \
            *(_Float16*)(lds + (PH) + sb) = (_Float16)e; \
        } \
    } \
} while (0)

template<bool DUAL>
__global__ __launch_bounds__(768, 4)
void main_kernel(const float* __restrict__ x, const _Float16* __restrict__ W,
                 const KArgs ka,
                 const float* __restrict__ alpha, const float* __restrict__ beta,
                 const float* __restrict__ sfp, const float* __restrict__ sop,
                 float* __restrict__ out)
{
    constexpr int PEH0 = 0, PEH1 = 9216;
    constexpr int PEL0 = 18432, PEL1 = 27648;          // dual only
    constexpr int RAWOFF = 0;                          // overlay, consumed before E writes
    constexpr int RAWSTR = 68;
    constexpr int LDSSZ = DUAL ? 36864 : 26112;        // >= RAW 26112, >= epi 21504
    __shared__ char lds[LDSSZ];

    const int kq = blockIdx.x, n = blockIdx.y, k0 = kq*KR;
    const int tid = threadIdx.x;
    const int wid = tid >> 6, lane = tid & 63, l15 = lane & 15, g = lane >> 4;
    const int ng = wid;
    const int t_e = wid, cc = lane;

    // ---- B register ring (depth 3): issue ASAP ----
    f16x8 br[3];
    BLOAD(0, 0); BLOAD(1, 1); BLOAD(2, 2);

    // ---- stage raw x rows (k0-1 .. k0+4) as biased u8, stride 68 ----
    #pragma unroll
    for (int j = 0; j < 7; ++j) {
        int idx = j*768 + tid;                   // < 5376 data words
        int row = idx / 14, w = idx - row*14;
        int krow = row >> 6;
        int ch = row & 63;
        int xr = k0 + krow - 1;
        u32 bword = 0x80808080u;
        if (xr >= 0 && xr < HWD) {
            const float4 vx = *(const float4*)(x + (((size_t)(n*CIN + ch))*HWD + xr)*HWD + w*4);
            bword = (u32)(int)(vx.x + 128.f) | ((u32)(int)(vx.y + 128.f) << 8)
                  | ((u32)(int)(vx.z + 128.f) << 16) | ((u32)(int)(vx.w + 128.f) << 24);
        }
        *(u32*)(lds + RAWOFF + row*RAWSTR + 4 + w*4) = bword;
    }
    #pragma unroll
    for (int jj = 0; jj < 2; ++jj) {             // pads: bytes 0..3, 60..67
        int p = jj*768 + tid;
        if (p < 1152) {
            int row = p/3, ws = p - row*3;
            int wb = (ws == 0) ? 0 : (56 + ws*4);
            *(u32*)(lds + RAWOFF + row*RAWSTR + wb) = 0x80808080u;
        }
    }
    WAITL(); SBAR();

    // ---- extract per-thread x window (t = wid, c = lane) into 12 packed u32 regs ----
    u32 xwL[6], xwH[6];
    {
        const int a0 = (5*t_e + 3) & ~7;
        const int sh = ((5*t_e + 3) & 7) * 8;
        #pragma unroll
        for (int krow = 0; krow < 6; ++krow) {
            const char* pb = lds + RAWOFF + (krow*64 + cc)*RAWSTR + a0;
            u64 lo = *(const u64*)pb;
            u64 hi = *(const u64*)(pb + 8);
            u64 wnd = (lo >> sh) | ((hi << 1) << (63 - sh));
            xwL[krow] = (u32)wnd;
            xwH[krow] = (u32)(wnd >> 32);
        }
    }
    WAITL(); SBAR();   // RAW fully consumed; plane region may be written

    // ---- E(0) into plane 0 ----
    E_BUILD(0, PEH0, PEL0);
    WAITL(); SBAR();

    // ---- accumulators ----
    f32x4 yu[5][3], mv[3];
    #pragma unroll
    for (int u = 0; u < 5; ++u)
        #pragma unroll
        for (int f = 0; f < 3; ++f) yu[u][f] = f32x4{0.f,0.f,0.f,0.f};
    #pragma unroll
    for (int f = 0; f < 3; ++f) mv[f] = f32x4{0.f,0.f,0.f,0.f};

    // ---- main loop: GEMM(v) from plane[v&1]; then E-build(v+1) -> plane[(v+1)&1]; 1 barrier ----
    #pragma unroll 1
    for (int v = 0; v < 7; ++v) {
        const int rEH = (v & 1) ? PEH1 : PEH0;
        const int rEL = (v & 1) ? PEL1 : PEL0;
        #pragma unroll
        for (int si = 0; si < 6; ++si) {
            const int sl = si % 3;               // static slot
            const int rr = si >> 1, chh = si & 1;
            f16x8 a0f, a1f, a2f;
            {
                const int r0 = rr*12 +  0 + l15;
                const int r1 = rr*12 + 16 + l15;
                const int r2 = rr*12 + 32 + l15;
                a0f = *(const f16x8*)(lds + rEH + r0*128 + ((((chh << 2) | g) ^ (r0 & 7)) << 4));
                a1f = *(const f16x8*)(lds + rEH + r1*128 + ((((chh << 2) | g) ^ (r1 & 7)) << 4));
                a2f = *(const f16x8*)(lds + rEH + r2*128 + ((((chh << 2) | g) ^ (r2 & 7)) << 4));
            }
            mv[0] = __builtin_amdgcn_mfma_f32_16x16x32_f16(a0f, br[sl], mv[0], 0,0,0);
            mv[1] = __builtin_amdgcn_mfma_f32_16x16x32_f16(a1f, br[sl], mv[1], 0,0,0);
            mv[2] = __builtin_amdgcn_mfma_f32_16x16x32_f16(a2f, br[sl], mv[2], 0,0,0);
            if (DUAL) {
                const int r0 = rr*12 +  0 + l15;
                const int r1 = rr*12 + 16 + l15;
                const int r2 = rr*12 + 32 + l15;
                f16x8 l0 = *(const f16x8*)(lds + rEL + r0*128 + ((((chh << 2) | g) ^ (r0 & 7)) << 4));
                f16x8 l1 = *(const f16x8*)(lds + rEL + r1*128 + ((((chh << 2) | g) ^ (r1 & 7)) << 4));
                f16x8 l2 = *(const f16x8*)(lds + rEL + r2*128 + ((((chh << 2) | g) ^ (r2 & 7)) << 4));
                mv[0] = __builtin_amdgcn_mfma_f32_16x16x32_f16(l0, br[sl], mv[0], 0,0,0);
                mv[1] = __builtin_amdgcn_mfma_f32_16x16x32_f16(l1, br[sl], mv[1], 0,0,0);
                mv[2] = __builtin_amdgcn_mfma_f32_16x16x32_f16(l2, br[sl], mv[2], 0,0,0);
            }
            // refill slot: 3-deep prefetch across v boundary
            if (si < 3) {
                BLOAD(v*6 + si + 3, sl);
            } else if (v < 6) {
                BLOAD((v+1)*6 + (si - 3), si - 3);
            }
        }
        // FOLD(v)
        {
            const float a0c = ATT[v][0], a1c = ATT[v][1], a2c = ATT[v][2];
            const float a3c = ATT[v][3], a4c = ATT[v][4];
            #pragma unroll
            for (int f = 0; f < 3; ++f) {
                yu[0][f] += a0c * mv[f];
                yu[1][f] += a1c * mv[f];
                yu[2][f] += a2c * mv[f];
                yu[3][f] += a3c * mv[f];
                yu[4][f] += a4c * mv[f];
                mv[f] = f32x4{0.f,0.f,0.f,0.f};
            }
        }
        // E-build for v+1 into the other plane (other waves may still be in GEMM(v))
        if (v < 6) {
            const int wEH = (v & 1) ? PEH0 : PEH1;
            const int wEL = (v & 1) ? PEL0 : PEL1;
            const int vv = v + 1;
            E_BUILD(vv, wEH, wEL);
        }
        WAITL(); SBAR();
    }

    // ---- epilogue: two 96-row o-half passes through a 21.5KB u8 buffer ----
    const float rdenom = 1.f / (120.f * sfp[0]);
    const int o = ng*16 + l15;
    const float avv = alpha[o];
    const float bev = rintf(beta[o] * sop[0]);
    unsigned char* ldsb = (unsigned char*)lds;    // [96][224] per pass
    #pragma unroll
    for (int h = 0; h < 2; ++h) {
        if ((ng / 6) == h) {
            const int olocal = (ng - h*6)*16 + l15;   // 0..95
            #pragma unroll
            for (int af = 0; af < 3; ++af) {
                #pragma unroll
                for (int q = 0; q < 4; ++q) {
                    const int m = af*16 + g*4 + q;    // 0..47
                    const int kl = m / 12, t = m - kl*12;
                    #pragma unroll
                    for (int u = 0; u < 5; ++u) {
                        const int col = t*5 + u;
                        if (col < HWD) {
                            float yv = yu[u][af][q];
                            yv = rintf(yv * rdenom);
                            yv = rintf(avv*yv) + bev;
                            yv = rintf(yv);
                            yv = fminf(fmaxf(yv, -128.f), 127.f);
                            yv = fmaxf(yv, 0.f);
                            ldsb[olocal*224 + kl*56 + col] = (unsigned char)(int)yv;
                        }
                    }
                }
            }
        }
        WAITL(); SBAR();
        // cooperative store of this half: 96*56 = 5376 u32 words -> float4
        #pragma unroll
        for (int it = 0; it < 7; ++it) {
            int i = it*768 + tid;                 // < 5376
            int o2 = i / 56, w = i - o2*56;
            int kl = w / 14, q4 = w - kl*14;
            u32 wb2 = *(const u32*)(ldsb + o2*224 + kl*56 + q4*4);
            float4 f;
            f.x = (float)(wb2 & 255u);
            f.y = (float)((wb2 >> 8) & 255u);
            f.z = (float)((wb2 >> 16) & 255u);
            f.w = (float)(wb2 >> 24);
            float* dst = out + (((size_t)(n*COUT + h*96 + o2))*HWD + (k0 + kl))*HWD + q4*4;
            *(float4*)dst = f;
        }
        SBAR();   // half buffer free before next pass writes
    }
}

extern "C" void kernel_launch(void* const* d_in, const int* in_sizes, int n_in,
                              void* d_out, int out_size, void* d_ws, size_t ws_size,
                              hipStream_t stream) {
    const float* x      = (const float*)d_in[0];
    const float* weight = (const float*)d_in[1];
    const float* alpha  = (const float*)d_in[2];
    const float* beta   = (const float*)d_in[3];
    const float* sf     = (const float*)d_in[4];
    const float* so     = (const float*)d_in[5];
    float* out = (float*)d_out;

    _Float16* Wp = (_Float16*)((char*)d_ws + WS_W_OFF);

    KArgs ka;
    bool dual;
    host_compute_bt(&ka, &dual);

    wt16_kernel<<<(32256 + 255)/256, 256, 0, stream>>>(weight, Wp);

    dim3 grid(NKQ, NBATCH);
    if (dual) {
        main_kernel<true><<<grid, 768, 0, stream>>>(x, Wp, ka, alpha, beta, sf, so, out);
    } else {
        main_kernel<false><<<grid, 768, 0, stream>>>(x, Wp, ka, alpha, beta, sf, so, out);
    }
}

// Round 19
// 84.927 us; speedup vs baseline: 1.9721x; 1.9721x over previous
//
#include <hip/hip_runtime.h>
#include <math.h>

typedef _Float16 f16x8 __attribute__((ext_vector_type(8)));
typedef float f32x4 __attribute__((ext_vector_type(4)));
typedef unsigned int u32;
typedef unsigned long long u64;

#define NBATCH 32
#define CIN    64
#define COUT   192
#define HWD    56
#define KR     4
#define NKQ    14

#define WS_W_OFF  1024

#define SBAR()  do { __builtin_amdgcn_s_barrier(); asm volatile("" ::: "memory"); } while(0)
#define WAITL() asm volatile("s_waitcnt lgkmcnt(0)" ::: "memory")

struct KArgs {
    float bt[49];
    float einit[7];
};

// AT transposed: ATT[v][u] = AT[u][v]
__device__ const float ATT[7][5] = {
    {1,0,0,0,0},{1,1,1,1,1},{1,-1,1,-1,1},{1,2,4,8,16},{1,-2,4,-8,16},{1,3,9,27,81},{0,0,0,0,1}};

// ---------------- Host: Householder QR lstsq for BT (f64) + range flag ----------------
static void host_compute_bt(KArgs* ka, bool* dual) {
    const double ATd[5][7] = {
        {1,1,1,1,1,1,0},{0,1,-1,2,-2,3,0},{0,1,1,4,4,9,0},{0,1,-1,8,-8,27,0},{0,1,1,16,16,81,1}};
    const double pts[6] = {0.0,1.0,-1.0,2.0,-2.0,3.0};
    double G[7][3];
    for (int i=0;i<6;i++){ G[i][0]=1.0; G[i][1]=pts[i]; G[i][2]=pts[i]*pts[i]; }
    G[6][0]=0.0; G[6][1]=0.0; G[6][2]=1.0;
    double M[15][7], T[15][7];
    for (int p=0;p<3;p++)
        for (int u=0;u<5;u++)
            for (int v=0;v<7;v++)
                M[5*p+u][v] = ATd[u][v]*G[v][p];
    for (int i=0;i<15;i++) for (int j=0;j<7;j++) T[i][j]=0.0;
    for (int p=0;p<3;p++) for (int kk=0;kk<5;kk++) T[5*p+kk][kk+p]=1.0;
    for (int j=0;j<7;j++){
        double sig=0.0; for (int i=j;i<15;i++) sig += M[i][j]*M[i][j];
        double nrm = sqrt(sig);
        double ajj = M[j][j];
        double alpha = (ajj > 0.0) ? -nrm : nrm;
        double v[15];
        v[j] = ajj - alpha;
        for (int i=j+1;i<15;i++) v[i] = M[i][j];
        double vtv = sig - 2.0*alpha*ajj + alpha*alpha;
        if (vtv > 1e-300) {
            double tau = 2.0/vtv;
            for (int c=j;c<7;c++){
                double s=0.0; for (int i=j;i<15;i++) s += v[i]*M[i][c];
                s *= tau;
                for (int i=j;i<15;i++) M[i][c] -= s*v[i];
            }
            for (int c=0;c<7;c++){
                double s=0.0; for (int i=j;i<15;i++) s += v[i]*T[i][c];
                s *= tau;
                for (int i=j;i<15;i++) T[i][c] -= s*v[i];
            }
        }
        M[j][j] = alpha;
        for (int i=j+1;i<15;i++) M[i][j]=0.0;
    }
    double btd[49];
    for (int c=0;c<7;c++){
        double xs[7];
        for (int i=6;i>=0;i--){
            double s = T[i][c];
            for (int k2=i+1;k2<7;k2++) s -= M[i][k2]*xs[k2];
            xs[i] = s / M[i][i];
        }
        for (int i=0;i<7;i++) btd[i*7+c] = xs[i];
    }
    for (int i=0;i<49;i++) ka->bt[i] = (float)btd[i];
    double mb = 0.0;
    for (int v=0;v<7;v++){
        double rs = 0.0;
        for (int c=0;c<7;c++) rs += fabs(btd[v*7+c]);
        if (rs > mb) mb = rs;
    }
    *dual = (mb * 128.0 > 8192.0);
    for (int v=0;v<7;v++){
        float s = ka->bt[v*7+0];
        for (int w=1;w<7;w++) s = s + ka->bt[v*7+w];
        ka->einit[v] = -128.f * s;
    }
}

// ---------------- Kernel: weight transform -> W4[v][step][ng4][frag3][lane][8] ----------------
// Per (v,step,ng): 3KB contiguous (3 frags x 1KB); o = ng*48 + bj*16 + l15, c = ch*32 + g*8 + e.
__global__ void wt16_kernel(const float* __restrict__ w, _Float16* __restrict__ W2) {
    int idx = blockIdx.x*256 + threadIdx.x;     // chunk id, < 7*6*4*3*64 = 32256
    if (idx >= 32256) return;
    const int lane = idx & 63;
    int t = idx >> 6;
    const int bj = t % 3; t /= 3;
    const int ng = t % 4; t /= 4;
    const int step = t % 6; t /= 6;
    const int v = t;
    const int l15 = lane & 15, g = lane >> 4;
    const int rr = step >> 1, ch = step & 1;
    const int o = ng*48 + bj*16 + l15;
    const float Gf[7][3] = {{1,0,0},{1,1,1},{1,-1,1},{1,2,4},{1,-2,4},{1,3,9},{0,0,1}};
    const float g0 = Gf[v][0], g1 = Gf[v][1], g2 = Gf[v][2];
    f16x8 outv;
    #pragma unroll
    for (int e = 0; e < 8; ++e) {
        const int c = ch*32 + g*8 + e;
        const float* wp = w + (((size_t)o*CIN + c)*3 + rr)*3;
        float val = wp[0]*g0 + wp[1]*g1 + wp[2]*g2;
        val = rintf(val);
        val = fminf(fmaxf(val, -32768.f), 32767.f);   // |val| <= 1664: exact fp16
        outv[e] = (_Float16)val;
    }
    *(f16x8*)(W2 + (size_t)idx*8) = outv;
}

// ---------------- Main kernel: 1024 threads (16 waves = 4/SIMD), padded-frag tiles ----------------
// Wave (mg,ng): output frag m' = mg*16 + t (t<12 real) x 48 cols (3 B-frags).
// Per step (rr,chh): 1 A ds_read (window krow=mg+rr) + 3 MFMA.

#define BLOAD(S, sl) do { \
    const _Float16* bp_ = W + ((size_t)((S)*4 + ng)*3)*512 + lane*8; \
    br[sl][0] = *(const f16x8*)(bp_); \
    br[sl][1] = *(const f16x8*)(bp_ + 512); \
    br[sl][2] = *(const f16x8*)(bp_ + 1024); \
} while (0)

template<bool DUAL>
__global__ __launch_bounds__(1024, 4)
void main_kernel(const float* __restrict__ x, const _Float16* __restrict__ W,
                 const KArgs ka,
                 const float* __restrict__ alpha, const float* __restrict__ beta,
                 const float* __restrict__ sfp, const float* __restrict__ sop,
                 float* __restrict__ out)
{
    extern __shared__ char lds[];
    constexpr int EHOFF = 0;
    constexpr int ELOFF = 66560;                       // dual only
    constexpr int RAWOFF = 0;                          // overlay, consumed before E writes
    constexpr int RAWSTR = 68;

    const int kq = blockIdx.x, n = blockIdx.y, k0 = kq*KR;
    const int tid = threadIdx.x;
    const int wid = tid >> 6, lane = tid & 63, l15 = lane & 15, g = lane >> 4;
    const int mg = wid & 3, ng = wid >> 2;             // 4 M-frags x 4 N-groups
    const int t_e = wid, cc = lane;                    // E-build role (wid < 12 only)

    // ---- B register ring (depth 3): issue ASAP ----
    f16x8 br[3][3];
    BLOAD(0, 0); BLOAD(1, 1); BLOAD(2, 2);

    // ---- stage raw x rows (k0-1 .. k0+4) as biased u8, stride 68 ----
    #pragma unroll
    for (int j = 0; j < 6; ++j) {
        int idx = j*1024 + tid;                  // < 5376 data words
        if (idx < 5376) {
            int row = idx / 14, w = idx - row*14;
            int krow = row >> 6;
            int ch = row & 63;
            int xr = k0 + krow - 1;
            u32 bword = 0x80808080u;
            if (xr >= 0 && xr < HWD) {
                const float4 vx = *(const float4*)(x + (((size_t)(n*CIN + ch))*HWD + xr)*HWD + w*4);
                bword = (u32)(int)(vx.x + 128.f) | ((u32)(int)(vx.y + 128.f) << 8)
                      | ((u32)(int)(vx.z + 128.f) << 16) | ((u32)(int)(vx.w + 128.f) << 24);
            }
            *(u32*)(lds + RAWOFF + row*RAWSTR + 4 + w*4) = bword;
        }
    }
    #pragma unroll
    for (int jj = 0; jj < 2; ++jj) {             // pads: bytes 0..3, 60..67
        int p = jj*1024 + tid;
        if (p < 1152) {
            int row = p/3, ws = p - row*3;
            int wb = (ws == 0) ? 0 : (56 + ws*4);
            *(u32*)(lds + RAWOFF + row*RAWSTR + wb) = 0x80808080u;
        }
    }
    WAITL(); SBAR();

    // ---- extract per-thread x window (wid<12: t = wid, c = lane) ----
    u32 xwL[6], xwH[6];
    if (wid < 12) {
        const int a0 = (5*t_e + 3) & ~7;
        const int sh = ((5*t_e + 3) & 7) * 8;
        #pragma unroll
        for (int krow = 0; krow < 6; ++krow) {
            const char* pb = lds + RAWOFF + (krow*64 + cc)*RAWSTR + a0;
            u64 lo = *(const u64*)pb;
            u64 hi = *(const u64*)(pb + 8);
            u64 wnd = (lo >> sh) | ((hi << 1) << (63 - sh));
            xwL[krow] = (u32)wnd;
            xwH[krow] = (u32)(wnd >> 32);
        }
    }
    WAITL(); SBAR();   // RAW fully consumed; E region (same bytes) may be written

    // ---- build the FULL E table (all 7 v); wids 12-15 idle here ----
    #pragma unroll 1
    for (int v = 0; v < 7; ++v) {
        if (wid < 12) {
            const float b0 = ka.bt[v*7+0], b1 = ka.bt[v*7+1], b2 = ka.bt[v*7+2];
            const float b3 = ka.bt[v*7+3], b4 = ka.bt[v*7+4], b5 = ka.bt[v*7+5], b6 = ka.bt[v*7+6];
            const float einit = ka.einit[v];
            #pragma unroll
            for (int krow = 0; krow < 6; ++krow) {
                const u32 Aw = xwL[krow], Bw = xwH[krow];
                float e = einit;
                e = fmaf(b0, (float)(Aw & 255u),         e);
                e = fmaf(b1, (float)((Aw >> 8) & 255u),  e);
                e = fmaf(b2, (float)((Aw >> 16) & 255u), e);
                e = fmaf(b3, (float)(Aw >> 24),          e);
                e = fmaf(b4, (float)(Bw & 255u),         e);
                e = fmaf(b5, (float)((Bw >> 8) & 255u),  e);
                e = fmaf(b6, (float)((Bw >> 16) & 255u), e);
                e = rintf(e);
                e = fminf(fmaxf(e, -32768.f), 32767.f);
                const int row = krow*12 + t_e;
                const int sb = v*9216 + row*128 + ((((cc >> 3) ^ (row & 7)) << 4) | ((cc & 7) << 1));
                if (DUAL) {
                    float ehs = rintf(e * (1.f/2048.f)) * 2048.f;
                    *(_Float16*)(lds + EHOFF + sb) = (_Float16)ehs;
                    *(_Float16*)(lds + ELOFF + sb) = (_Float16)(e - ehs);
                } else {
                    *(_Float16*)(lds + EHOFF + sb) = (_Float16)e;
                }
            }
        }
    }
    WAITL(); SBAR();    // E table published; barrier-free GEMM follows

    // ---- accumulators: 1 M-frag x 3 N-frags ----
    f32x4 yu[5][3], mv[3];
    #pragma unroll
    for (int u = 0; u < 5; ++u)
        #pragma unroll
        for (int f = 0; f < 3; ++f) yu[u][f] = f32x4{0.f,0.f,0.f,0.f};
    #pragma unroll
    for (int f = 0; f < 3; ++f) mv[f] = f32x4{0.f,0.f,0.f,0.f};

    // ---- barrier-free main loop: 7 v x 6 steps; A window krow = mg + rr ----
    #pragma unroll 1
    for (int v = 0; v < 7; ++v) {
        #pragma unroll
        for (int si = 0; si < 6; ++si) {
            const int sl = si % 3;               // static ring slot
            const int rr = si >> 1, chh = si & 1;
            const int arow = (mg + rr)*12 + l15;
            const int ab = v*9216 + arow*128 + ((((chh << 2) | g) ^ (arow & 7)) << 4);
            f16x8 af = *(const f16x8*)(lds + EHOFF + ab);
            mv[0] = __builtin_amdgcn_mfma_f32_16x16x32_f16(af, br[sl][0], mv[0], 0,0,0);
            mv[1] = __builtin_amdgcn_mfma_f32_16x16x32_f16(af, br[sl][1], mv[1], 0,0,0);
            mv[2] = __builtin_amdgcn_mfma_f32_16x16x32_f16(af, br[sl][2], mv[2], 0,0,0);
            if (DUAL) {
                f16x8 al = *(const f16x8*)(lds + ELOFF + ab);
                mv[0] = __builtin_amdgcn_mfma_f32_16x16x32_f16(al, br[sl][0], mv[0], 0,0,0);
                mv[1] = __builtin_amdgcn_mfma_f32_16x16x32_f16(al, br[sl][1], mv[1], 0,0,0);
                mv[2] = __builtin_amdgcn_mfma_f32_16x16x32_f16(al, br[sl][2], mv[2], 0,0,0);
            }
            // refill: 3-deep prefetch across v boundary
            if (si < 3) {
                BLOAD(v*6 + si + 3, sl);
            } else if (v < 6) {
                BLOAD((v+1)*6 + (si - 3), si - 3);
            }
        }
        // FOLD(v)
        {
            const float a0c = ATT[v][0], a1c = ATT[v][1], a2c = ATT[v][2];
            const float a3c = ATT[v][3], a4c = ATT[v][4];
            #pragma unroll
            for (int f = 0; f < 3; ++f) {
                yu[0][f] += a0c * mv[f];
                yu[1][f] += a1c * mv[f];
                yu[2][f] += a2c * mv[f];
                yu[3][f] += a3c * mv[f];
                yu[4][f] += a4c * mv[f];
                mv[f] = f32x4{0.f,0.f,0.f,0.f};
            }
        }
    }

    SBAR();   // all waves done reading the E table; LDS reusable for epilogue

    // ---- epilogue: quantize to u8 in LDS; frag m' = mg*16 + p, p = g*4+q real iff g<3 ----
    const float rdenom = 1.f / (120.f * sfp[0]);
    unsigned char* ldsb = (unsigned char*)lds;    // [192][224]
    if (g < 3) {
        const int t = g*4;                        // base t for q=0..3
        #pragma unroll
        for (int bj = 0; bj < 3; ++bj) {
            const int o = ng*48 + bj*16 + l15;
            const float avv = alpha[o];
            const float bev = rintf(beta[o] * sop[0]);
            #pragma unroll
            for (int q = 0; q < 4; ++q) {
                #pragma unroll
                for (int u = 0; u < 5; ++u) {
                    const int col = (t + q)*5 + u;
                    if (col < HWD) {
                        float yv = yu[u][bj][q];
                        yv = rintf(yv * rdenom);
                        yv = rintf(avv*yv) + bev;
                        yv = rintf(yv);
                        yv = fminf(fmaxf(yv, -128.f), 127.f);
                        yv = fmaxf(yv, 0.f);
                        ldsb[o*224 + mg*56 + col] = (unsigned char)(int)yv;
                    }
                }
            }
        }
    }
    WAITL(); SBAR();
    float* ob = out + ((size_t)(n*COUT))*3136 + k0*56;
    #pragma unroll
    for (int it = 0; it < 11; ++it) {
        int i = it*1024 + tid;                    // < 10752 quads
        if (i < 10752) {
            int o2 = i / 56, q4 = i - o2*56;
            u32 wb2 = *(const u32*)(ldsb + o2*224 + q4*4);
            float4 f;
            f.x = (float)(wb2 & 255u);
            f.y = (float)((wb2 >> 8) & 255u);
            f.z = (float)((wb2 >> 16) & 255u);
            f.w = (float)(wb2 >> 24);
            *(float4*)(ob + (size_t)o2*3136 + q4*4) = f;
        }
    }
}

extern "C" void kernel_launch(void* const* d_in, const int* in_sizes, int n_in,
                              void* d_out, int out_size, void* d_ws, size_t ws_size,
                              hipStream_t stream) {
    const float* x      = (const float*)d_in[0];
    const float* weight = (const float*)d_in[1];
    const float* alpha  = (const float*)d_in[2];
    const float* beta   = (const float*)d_in[3];
    const float* sf     = (const float*)d_in[4];
    const float* so     = (const float*)d_in[5];
    float* out = (float*)d_out;

    _Float16* Wp = (_Float16*)((char*)d_ws + WS_W_OFF);

    KArgs ka;
    bool dual;
    host_compute_bt(&ka, &dual);

    wt16_kernel<<<(32256 + 255)/256, 256, 0, stream>>>(weight, Wp);

    dim3 grid(NKQ, NBATCH);
    if (dual) {
        (void)hipFuncSetAttribute((const void*)&main_kernel<true>,
                                  hipFuncAttributeMaxDynamicSharedMemorySize, 133120);
        main_kernel<true><<<grid, 1024, 133120, stream>>>(x, Wp, ka, alpha, beta, sf, so, out);
    } else {
        (void)hipFuncSetAttribute((const void*)&main_kernel<false>,
                                  hipFuncAttributeMaxDynamicSharedMemorySize, 66560);
        main_kernel<false><<<grid, 1024, 66560, stream>>>(x, Wp, ka, alpha, beta, sf, so, out);
    }
}

// Round 20
// 82.673 us; speedup vs baseline: 2.0258x; 1.0273x over previous
//
#include <hip/hip_runtime.h>
#include <math.h>

typedef _Float16 f16x8 __attribute__((ext_vector_type(8)));
typedef float f32x4 __attribute__((ext_vector_type(4)));
typedef unsigned int u32;
typedef unsigned long long u64;

#define NBATCH 32
#define CIN    64
#define COUT   192
#define HWD    56
#define KR     4
#define NKQ    14

#define WS_W_OFF  1024

#define SBAR()  do { __builtin_amdgcn_s_barrier(); asm volatile("" ::: "memory"); } while(0)
#define WAITL() asm volatile("s_waitcnt lgkmcnt(0)" ::: "memory")

struct KArgs {
    float bt[49];
    float einit[7];
};

// AT transposed: ATT[v][u] = AT[u][v]
__device__ const float ATT[7][5] = {
    {1,0,0,0,0},{1,1,1,1,1},{1,-1,1,-1,1},{1,2,4,8,16},{1,-2,4,-8,16},{1,3,9,27,81},{0,0,0,0,1}};

// ---------------- Host: Householder QR lstsq for BT (f64) + range flag ----------------
static void host_compute_bt(KArgs* ka, bool* dual) {
    const double ATd[5][7] = {
        {1,1,1,1,1,1,0},{0,1,-1,2,-2,3,0},{0,1,1,4,4,9,0},{0,1,-1,8,-8,27,0},{0,1,1,16,16,81,1}};
    const double pts[6] = {0.0,1.0,-1.0,2.0,-2.0,3.0};
    double G[7][3];
    for (int i=0;i<6;i++){ G[i][0]=1.0; G[i][1]=pts[i]; G[i][2]=pts[i]*pts[i]; }
    G[6][0]=0.0; G[6][1]=0.0; G[6][2]=1.0;
    double M[15][7], T[15][7];
    for (int p=0;p<3;p++)
        for (int u=0;u<5;u++)
            for (int v=0;v<7;v++)
                M[5*p+u][v] = ATd[u][v]*G[v][p];
    for (int i=0;i<15;i++) for (int j=0;j<7;j++) T[i][j]=0.0;
    for (int p=0;p<3;p++) for (int kk=0;kk<5;kk++) T[5*p+kk][kk+p]=1.0;
    for (int j=0;j<7;j++){
        double sig=0.0; for (int i=j;i<15;i++) sig += M[i][j]*M[i][j];
        double nrm = sqrt(sig);
        double ajj = M[j][j];
        double alpha = (ajj > 0.0) ? -nrm : nrm;
        double v[15];
        v[j] = ajj - alpha;
        for (int i=j+1;i<15;i++) v[i] = M[i][j];
        double vtv = sig - 2.0*alpha*ajj + alpha*alpha;
        if (vtv > 1e-300) {
            double tau = 2.0/vtv;
            for (int c=j;c<7;c++){
                double s=0.0; for (int i=j;i<15;i++) s += v[i]*M[i][c];
                s *= tau;
                for (int i=j;i<15;i++) M[i][c] -= s*v[i];
            }
            for (int c=0;c<7;c++){
                double s=0.0; for (int i=j;i<15;i++) s += v[i]*T[i][c];
                s *= tau;
                for (int i=j;i<15;i++) T[i][c] -= s*v[i];
            }
        }
        M[j][j] = alpha;
        for (int i=j+1;i<15;i++) M[i][j]=0.0;
    }
    double btd[49];
    for (int c=0;c<7;c++){
        double xs[7];
        for (int i=6;i>=0;i--){
            double s = T[i][c];
            for (int k2=i+1;k2<7;k2++) s -= M[i][k2]*xs[k2];
            xs[i] = s / M[i][i];
        }
        for (int i=0;i<7;i++) btd[i*7+c] = xs[i];
    }
    for (int i=0;i<49;i++) ka->bt[i] = (float)btd[i];
    double mb = 0.0;
    for (int v=0;v<7;v++){
        double rs = 0.0;
        for (int c=0;c<7;c++) rs += fabs(btd[v*7+c]);
        if (rs > mb) mb = rs;
    }
    *dual = (mb * 128.0 > 8192.0);
    for (int v=0;v<7;v++){
        float s = ka->bt[v*7+0];
        for (int w=1;w<7;w++) s = s + ka->bt[v*7+w];
        ka->einit[v] = -128.f * s;
    }
}

// ---------------- Kernel: weight transform -> per-(step,ng12) 1KB frag layout ----------------
__global__ void wt16_kernel(const float* __restrict__ w, _Float16* __restrict__ W3) {
    int idx = blockIdx.x*256 + threadIdx.x;     // chunk id, < 7*6*12*64 = 32256
    if (idx >= 32256) return;
    const int lane = idx & 63;
    int t = idx >> 6;
    const int ng = t % 12; t /= 12;
    const int step = t % 6; t /= 6;
    const int v = t;
    const int l15 = lane & 15, g = lane >> 4;
    const int rr = step >> 1, ch = step & 1;
    const int o = ng*16 + l15;
    const float Gf[7][3] = {{1,0,0},{1,1,1},{1,-1,1},{1,2,4},{1,-2,4},{1,3,9},{0,0,1}};
    const float g0 = Gf[v][0], g1 = Gf[v][1], g2 = Gf[v][2];
    f16x8 outv;
    #pragma unroll
    for (int e = 0; e < 8; ++e) {
        const int c = ch*32 + g*8 + e;
        const float* wp = w + (((size_t)o*CIN + c)*3 + rr)*3;
        float val = wp[0]*g0 + wp[1]*g1 + wp[2]*g2;
        val = rintf(val);
        val = fminf(fmaxf(val, -32768.f), 32767.f);
        outv[e] = (_Float16)val;
    }
    *(f16x8*)(W3 + (size_t)idx*8) = outv;
}

// ---------------- Main kernel: 2-plane ping-pong S||G slip at (768,3) ----------------
// Per v: GEMM(v) from plane[v&1], then E_BUILD(v+1) -> plane[(v+1)&1], one barrier.
// Phases sequential PER WAVE (register sets don't union); waves slip across phases.

#define BLOAD(S, sl) do { \
    br[sl] = *(const f16x8*)(W + (size_t)((S)*12 + ng)*512 + lane*8); \
} while (0)

#define E_BUILD(vv, PH, PL) do { \
    const float b0 = ka.bt[(vv)*7+0], b1 = ka.bt[(vv)*7+1], b2 = ka.bt[(vv)*7+2]; \
    const float b3 = ka.bt[(vv)*7+3], b4 = ka.bt[(vv)*7+4], b5 = ka.bt[(vv)*7+5]; \
    const float b6 = ka.bt[(vv)*7+6]; \
    const float einit = ka.einit[(vv)]; \
    _Pragma("unroll") \
    for (int krow = 0; krow < 6; ++krow) { \
        const u32 Aw = xwL[krow], Bw = xwH[krow]; \
        float e = einit; \
        e = fmaf(b0, (float)(Aw & 255u),         e); \
        e = fmaf(b1, (float)((Aw >> 8) & 255u),  e); \
        e = fmaf(b2, (float)((Aw >> 16) & 255u), e); \
        e = fmaf(b3, (float)(Aw >> 24),          e); \
        e = fmaf(b4, (float)(Bw & 255u),         e); \
        e = fmaf(b5, (float)((Bw >> 8) & 255u),  e); \
        e = fmaf(b6, (float)((Bw >> 16) & 255u), e); \
        e = rintf(e); \
        e = fminf(fmaxf(e, -32768.f), 32767.f); \
        const int row = krow*12 + t_e; \
        const int sb = row*128 + ((((cc >> 3) ^ (row & 7)) << 4) | ((cc & 7) << 1)); \
        if (DUAL) { \
            float ehs = rintf(e * (1.f/2048.f)) * 2048.f; \
            *(_Float16*)(lds + (PH) + sb) = (_Float16)ehs; \
            *(_Float16*)(lds + (PL) + sb) = (_Float16)(e - ehs); \
        } else { \
            *(_Float16*)(lds + (PH) + sb) = (_Float16)e; \
        } \
    } \
} while (0)

template<bool DUAL>
__global__ __launch_bounds__(768, 3)
void main_kernel(const float* __restrict__ x, const _Float16* __restrict__ W,
                 const KArgs ka,
                 const float* __restrict__ alpha, const float* __restrict__ beta,
                 const float* __restrict__ sfp, const float* __restrict__ sop,
                 float* __restrict__ out)
{
    constexpr int PEH0 = 0, PEH1 = 9216;
    constexpr int PEL0 = 18432, PEL1 = 27648;          // dual only
    constexpr int RAWOFF = 0;                          // overlay, consumed before E writes
    constexpr int RAWSTR = 68;
    constexpr int LDSSZ = DUAL ? 36864 : 26112;        // >= RAW 26112, >= epi-half 21504
    __shared__ char lds[LDSSZ];

    const int kq = blockIdx.x, n = blockIdx.y, k0 = kq*KR;
    const int tid = threadIdx.x;
    const int wid = tid >> 6, lane = tid & 63, l15 = lane & 15, g = lane >> 4;
    const int ng = wid;                                // wave = one 16-col o-group
    const int t_e = wid, cc = lane;

    // ---- B register ring (depth 6): issue ASAP ----
    f16x8 br[6];
    BLOAD(0, 0); BLOAD(1, 1); BLOAD(2, 2); BLOAD(3, 3); BLOAD(4, 4); BLOAD(5, 5);

    // ---- stage raw x rows (k0-1 .. k0+4) as biased u8, stride 68 ----
    #pragma unroll
    for (int j = 0; j < 7; ++j) {
        int idx = j*768 + tid;                   // < 5376 data words
        int row = idx / 14, w = idx - row*14;
        int krow = row >> 6;
        int ch = row & 63;
        int xr = k0 + krow - 1;
        u32 bword = 0x80808080u;
        if (xr >= 0 && xr < HWD) {
            const float4 vx = *(const float4*)(x + (((size_t)(n*CIN + ch))*HWD + xr)*HWD + w*4);
            bword = (u32)(int)(vx.x + 128.f) | ((u32)(int)(vx.y + 128.f) << 8)
                  | ((u32)(int)(vx.z + 128.f) << 16) | ((u32)(int)(vx.w + 128.f) << 24);
        }
        *(u32*)(lds + RAWOFF + row*RAWSTR + 4 + w*4) = bword;
    }
    #pragma unroll
    for (int jj = 0; jj < 2; ++jj) {             // pads: bytes 0..3, 60..67
        int p = jj*768 + tid;
        if (p < 1152) {
            int row = p/3, ws = p - row*3;
            int wb = (ws == 0) ? 0 : (56 + ws*4);
            *(u32*)(lds + RAWOFF + row*RAWSTR + wb) = 0x80808080u;
        }
    }
    WAITL(); SBAR();

    // ---- extract per-thread x window (t = wid, c = lane) into 12 packed u32 regs ----
    u32 xwL[6], xwH[6];
    {
        const int a0 = (5*t_e + 3) & ~7;
        const int sh = ((5*t_e + 3) & 7) * 8;
        #pragma unroll
        for (int krow = 0; krow < 6; ++krow) {
            const char* pb = lds + RAWOFF + (krow*64 + cc)*RAWSTR + a0;
            u64 lo = *(const u64*)pb;
            u64 hi = *(const u64*)(pb + 8);
            u64 wnd = (lo >> sh) | ((hi << 1) << (63 - sh));
            xwL[krow] = (u32)wnd;
            xwH[krow] = (u32)(wnd >> 32);
        }
    }
    WAITL(); SBAR();   // RAW fully consumed; plane region may be written

    // ---- E(0) into plane 0 ----
    E_BUILD(0, PEH0, PEL0);
    WAITL(); SBAR();

    // ---- accumulators: 3 A-frags x 1 B-frag ----
    f32x4 yu[5][3], mv[3];
    #pragma unroll
    for (int u = 0; u < 5; ++u)
        #pragma unroll
        for (int f = 0; f < 3; ++f) yu[u][f] = f32x4{0.f,0.f,0.f,0.f};
    #pragma unroll
    for (int f = 0; f < 3; ++f) mv[f] = f32x4{0.f,0.f,0.f,0.f};

    // ---- main loop: GEMM(v) ; E_BUILD(v+1) ; barrier ----
    #pragma unroll 1
    for (int v = 0; v < 7; ++v) {
        const int rEH = (v & 1) ? PEH1 : PEH0;
        const int rEL = (v & 1) ? PEL1 : PEL0;
        #pragma unroll
        for (int si = 0; si < 6; ++si) {
            const int rr = si >> 1, chh = si & 1;
            f16x8 a0f, a1f, a2f;
            {
                const int r0 = rr*12 +  0 + l15;
                const int r1 = rr*12 + 16 + l15;
                const int r2 = rr*12 + 32 + l15;
                a0f = *(const f16x8*)(lds + rEH + r0*128 + ((((chh << 2) | g) ^ (r0 & 7)) << 4));
                a1f = *(const f16x8*)(lds + rEH + r1*128 + ((((chh << 2) | g) ^ (r1 & 7)) << 4));
                a2f = *(const f16x8*)(lds + rEH + r2*128 + ((((chh << 2) | g) ^ (r2 & 7)) << 4));
            }
            mv[0] = __builtin_amdgcn_mfma_f32_16x16x32_f16(a0f, br[si], mv[0], 0,0,0);
            mv[1] = __builtin_amdgcn_mfma_f32_16x16x32_f16(a1f, br[si], mv[1], 0,0,0);
            mv[2] = __builtin_amdgcn_mfma_f32_16x16x32_f16(a2f, br[si], mv[2], 0,0,0);
            if (DUAL) {
                const int r0 = rr*12 +  0 + l15;
                const int r1 = rr*12 + 16 + l15;
                const int r2 = rr*12 + 32 + l15;
                f16x8 l0 = *(const f16x8*)(lds + rEL + r0*128 + ((((chh << 2) | g) ^ (r0 & 7)) << 4));
                f16x8 l1 = *(const f16x8*)(lds + rEL + r1*128 + ((((chh << 2) | g) ^ (r1 & 7)) << 4));
                f16x8 l2 = *(const f16x8*)(lds + rEL + r2*128 + ((((chh << 2) | g) ^ (r2 & 7)) << 4));
                mv[0] = __builtin_amdgcn_mfma_f32_16x16x32_f16(l0, br[si], mv[0], 0,0,0);
                mv[1] = __builtin_amdgcn_mfma_f32_16x16x32_f16(l1, br[si], mv[1], 0,0,0);
                mv[2] = __builtin_amdgcn_mfma_f32_16x16x32_f16(l2, br[si], mv[2], 0,0,0);
            }
            // refill slot si with same step of next v (6-step prefetch distance)
            if (v < 6) BLOAD((v+1)*6 + si, si);
        }
        // FOLD(v)
        {
            const float a0c = ATT[v][0], a1c = ATT[v][1], a2c = ATT[v][2];
            const float a3c = ATT[v][3], a4c = ATT[v][4];
            #pragma unroll
            for (int f = 0; f < 3; ++f) {
                yu[0][f] += a0c * mv[f];
                yu[1][f] += a1c * mv[f];
                yu[2][f] += a2c * mv[f];
                yu[3][f] += a3c * mv[f];
                yu[4][f] += a4c * mv[f];
                mv[f] = f32x4{0.f,0.f,0.f,0.f};
            }
        }
        // E-build v+1 into the other plane (sequential per wave; waves slip)
        if (v < 6) {
            const int wEH = (v & 1) ? PEH0 : PEH1;
            const int wEL = (v & 1) ? PEL0 : PEL1;
            const int vv = v + 1;
            E_BUILD(vv, wEH, wEL);
        }
        WAITL(); SBAR();
    }

    // ---- epilogue: two 96-row o-half passes through a 21.5KB u8 buffer ----
    const float rdenom = 1.f / (120.f * sfp[0]);
    const int o = ng*16 + l15;
    const float avv = alpha[o];
    const float bev = rintf(beta[o] * sop[0]);
    unsigned char* ldsb = (unsigned char*)lds;    // [96][224] per pass
    #pragma unroll
    for (int h = 0; h < 2; ++h) {
        if ((ng / 6) == h) {
            const int olocal = (ng - h*6)*16 + l15;   // 0..95
            #pragma unroll
            for (int af = 0; af < 3; ++af) {
                #pragma unroll
                for (int q = 0; q < 4; ++q) {
                    const int m = af*16 + g*4 + q;    // 0..47
                    const int kl = m / 12, t = m - kl*12;
                    #pragma unroll
                    for (int u = 0; u < 5; ++u) {
                        const int col = t*5 + u;
                        if (col < HWD) {
                            float yv = yu[u][af][q];
                            yv = rintf(yv * rdenom);
                            yv = rintf(avv*yv) + bev;
                            yv = rintf(yv);
                            yv = fminf(fmaxf(yv, -128.f), 127.f);
                            yv = fmaxf(yv, 0.f);
                            ldsb[olocal*224 + kl*56 + col] = (unsigned char)(int)yv;
                        }
                    }
                }
            }
        }
        WAITL(); SBAR();
        // cooperative store of this half: 96*56 = 5376 u32 words -> float4
        #pragma unroll
        for (int it = 0; it < 7; ++it) {
            int i = it*768 + tid;                 // < 5376
            int o2 = i / 56, w = i - o2*56;
            int kl = w / 14, q4 = w - kl*14;
            u32 wb2 = *(const u32*)(ldsb + o2*224 + kl*56 + q4*4);
            float4 f;
            f.x = (float)(wb2 & 255u);
            f.y = (float)((wb2 >> 8) & 255u);
            f.z = (float)((wb2 >> 16) & 255u);
            f.w = (float)(wb2 >> 24);
            float* dst = out + (((size_t)(n*COUT + h*96 + o2))*HWD + (k0 + kl))*HWD + q4*4;
            *(float4*)dst = f;
        }
        SBAR();   // half buffer free before next pass writes
    }
}

extern "C" void kernel_launch(void* const* d_in, const int* in_sizes, int n_in,
                              void* d_out, int out_size, void* d_ws, size_t ws_size,
                              hipStream_t stream) {
    const float* x      = (const float*)d_in[0];
    const float* weight = (const float*)d_in[1];
    const float* alpha  = (const float*)d_in[2];
    const float* beta   = (const float*)d_in[3];
    const float* sf     = (const float*)d_in[4];
    const float* so     = (const float*)d_in[5];
    float* out = (float*)d_out;

    _Float16* Wp = (_Float16*)((char*)d_ws + WS_W_OFF);

    KArgs ka;
    bool dual;
    host_compute_bt(&ka, &dual);

    wt16_kernel<<<(32256 + 255)/256, 256, 0, stream>>>(weight, Wp);

    dim3 grid(NKQ, NBATCH);
    if (dual) {
        main_kernel<true><<<grid, 768, 0, stream>>>(x, Wp, ka, alpha, beta, sf, so, out);
    } else {
        main_kernel<false><<<grid, 768, 0, stream>>>(x, Wp, ka, alpha, beta, sf, so, out);
    }
}